// Round 7
// baseline (1121.447 us; speedup 1.0000x reference)
//
#include <hip/hip_runtime.h>
#include <hip/hip_bf16.h>

// GCN: h1 = relu(Â (x W1) + b1); h2 = relu(Â (h1 W2) + b2);
// out = mean_pool(h2, batch) @ Wlin + blin,  Â = D^-1/2 (A+I) D^-1/2
//
// R2: per-graph counts via sorted-batch boundaries.
// R3: norm folded into gemm epilogue (xws = dinv*xw); agg unrolled x4.
// R5/R6: bucketed CSR build, deterministic two-pass, zero global atomics.
// R7: xws stored bf16 -> agg row-gather is 128 B not 256 B (agg was 72 us,
//     FETCH 190 MB, byte-bound at 3 TB/s). gemm rewritten: 64x64 tile,
//     4x4 per thread, float4 LDS reads of W (old: 64 scalar stride-256B
//     ds_read per thread). bscatter ECHUNK 8192->16384 (less cross-XCD
//     partial-line writeback).

#define NDIM 64
#define NGRAPH 64
#define BSHIFT 7                      // 128 nodes per bucket
#define BNODES 128
#define ECHUNK 16384                  // edges per block in bincnt/bscatter (64/thread)

// ---- pass 1: per-(block,bucket) edge counts via LDS histogram ----
__global__ void bincnt_k(const int* __restrict__ dst, int* __restrict__ cntmat,
                         int e, int nb) {
    extern __shared__ int hist[];
    int t = threadIdx.x;
    for (int i = t; i < nb; i += 256) hist[i] = 0;
    __syncthreads();
    int base = blockIdx.x * ECHUNK + t;
#pragma unroll
    for (int k = 0; k < 64; ++k) {
        int i = base + k * 256;
        if (i < e) atomicAdd(&hist[dst[i] >> BSHIFT], 1);   // LDS atomic
    }
    __syncthreads();
    long row = (long)blockIdx.x * nb;
    for (int i = t; i < nb; i += 256) cntmat[row + i] = hist[i];
}

// ---- pass 2: per-bucket exclusive scan across blocks (one block per bucket) ----
// requires nblk <= 256
__global__ void colscan_k(const int* __restrict__ cntmat, int* __restrict__ basemat,
                          int* __restrict__ bucketTot, int nblk, int nb) {
    __shared__ int s[256];
    int b = blockIdx.x;
    int t = threadIdx.x;
    int v = (t < nblk) ? cntmat[(long)t * nb + b] : 0;
    s[t] = v;
    __syncthreads();
    for (int off = 1; off < 256; off <<= 1) {
        int tmp = (t >= off) ? s[t - off] : 0;
        __syncthreads();
        s[t] += tmp;
        __syncthreads();
    }
    if (t < nblk) basemat[(long)t * nb + b] = s[t] - v;   // exclusive within column
    if (t == 255) bucketTot[b] = s[255];
}

// ---- pass 3: exclusive scan of bucket totals (single block, nb<=1024) ----
__global__ void bscan_k(const int* __restrict__ bucketTot, int* __restrict__ bucketStart,
                        int* __restrict__ start, int nb, int n, int e) {
    __shared__ int s[1024];
    int t = threadIdx.x;
    int v = (t < nb) ? bucketTot[t] : 0;
    s[t] = v;
    __syncthreads();
    for (int off = 1; off < 1024; off <<= 1) {
        int tmp = (t >= off) ? s[t - off] : 0;
        __syncthreads();
        s[t] += tmp;
        __syncthreads();
    }
    if (t < nb) bucketStart[t + 1] = s[t];
    if (t == 0) { bucketStart[0] = 0; start[n] = e; }   // CSR sentinel
}

// ---- pass 4: scatter packed (dst_local<<25 | src) via block-private LDS cursors ----
// MUST use the same edge->block assignment as bincnt_k.
__global__ void bscatter_k(const int* __restrict__ src, const int* __restrict__ dst,
                           const int* __restrict__ bucketStart,
                           const int* __restrict__ basemat,
                           unsigned int* __restrict__ ebuf, int e, int nb) {
    extern __shared__ int cur[];
    int t = threadIdx.x;
    long row = (long)blockIdx.x * nb;
    for (int i = t; i < nb; i += 256) cur[i] = bucketStart[i] + basemat[row + i];
    __syncthreads();
    int base = blockIdx.x * ECHUNK + t;
#pragma unroll
    for (int k = 0; k < 64; ++k) {
        int i = base + k * 256;
        if (i < e) {
            int d = dst[i];
            int b = d >> BSHIFT;
            int pos = atomicAdd(&cur[b], 1);               // LDS atomic, block-private
            ebuf[pos] = ((unsigned)(d & (BNODES - 1)) << 25) | (unsigned)src[i];
        }
    }
}

// ---- pass 5: one block per bucket -> dst-ordered CSR slice, dinv, graph ranges ----
__global__ void fill2_k(const unsigned int* __restrict__ ebuf,
                        const int* __restrict__ bucketStart,
                        const int* __restrict__ batch, float* __restrict__ dinv,
                        int* __restrict__ start, int* __restrict__ csr,
                        int* __restrict__ gstart, int* __restrict__ gend, int n) {
    __shared__ int scnt[BNODES], sincl[BNODES], scur[BNODES];
    int t = threadIdx.x;
    int b = blockIdx.x;
    int node0 = b << BSHIFT;
    int nNodes = min(BNODES, n - node0);
    if (t < BNODES) scnt[t] = 0;
    int e0 = bucketStart[b], e1 = bucketStart[b + 1];
    __syncthreads();
    for (int i = e0 + t; i < e1; i += 256)
        atomicAdd(&scnt[ebuf[i] >> 25], 1);
    __syncthreads();
    int val = (t < BNODES) ? scnt[t] : 0;
    if (t < BNODES) sincl[t] = val;
    __syncthreads();
    for (int off = 1; off < BNODES; off <<= 1) {
        int tmp = (t >= off && t < BNODES) ? sincl[t - off] : 0;
        __syncthreads();
        if (t < BNODES) sincl[t] += tmp;
        __syncthreads();
    }
    if (t < nNodes) {
        int v = node0 + t;
        int st = e0 + sincl[t] - val;     // exclusive within bucket
        start[v] = st;
        scur[t] = st;
        dinv[v] = rsqrtf((float)(val + 1));
        int g = batch[v];                 // sorted-batch boundary detection
        if (v == 0 || batch[v - 1] != g) gstart[g] = v;
        if (v == n - 1 || batch[v + 1] != g) gend[g] = v + 1;
    }
    __syncthreads();
    for (int i = e0 + t; i < e1; i += 256) {
        unsigned rec = ebuf[i];
        int pos = atomicAdd(&scur[rec >> 25], 1);
        csr[pos] = (int)(rec & 0x1FFFFFFu);   // scatter within L2-local 8 KB slice
    }
}

// ---- dense GEMM  C[n,64](bf16) = scale[row] * (A[n,64] @ W[64,64]) ----
// 64x64 tile per block, 4x4 outputs per thread, float4 LDS reads of W.
__global__ void gemm_k(const float* __restrict__ A, const float* __restrict__ W,
                       const float* __restrict__ scale, __hip_bfloat16* __restrict__ C,
                       int n) {
    __shared__ float4 Wl4[64 * 16];   // W row-major as float4: W[k][4c..4c+3]
    __shared__ float  Xl[64 * 64];    // 64 rows of A
    int t = threadIdx.x;
    const float4* W4 = (const float4*)W;
#pragma unroll
    for (int i = 0; i < 4; ++i) Wl4[t + 256 * i] = W4[t + 256 * i];
    long fbase = (long)blockIdx.x * 1024;            // in float4 units
    long fmax  = (long)n * (NDIM / 4);
    float4* Xl4 = (float4*)Xl;
#pragma unroll
    for (int i = 0; i < 4; ++i) {
        long f = fbase + t + 256 * i;
        float4 v = {0.f, 0.f, 0.f, 0.f};
        if (f < fmax) v = ((const float4*)A)[f];
        Xl4[t + 256 * i] = v;
    }
    __syncthreads();
    int cg = t & 15;          // 16 col groups x 4 cols
    int rg = t >> 4;          // 16 row groups x 4 rows
    float4 acc[4] = {{0,0,0,0},{0,0,0,0},{0,0,0,0},{0,0,0,0}};
#pragma unroll
    for (int k = 0; k < 64; ++k) {
        float4 w = Wl4[k * 16 + cg];
#pragma unroll
        for (int r = 0; r < 4; ++r) {
            float xv = Xl[(rg * 4 + r) * 64 + k];
            acc[r].x += xv * w.x;
            acc[r].y += xv * w.y;
            acc[r].z += xv * w.z;
            acc[r].w += xv * w.w;
        }
    }
    int vbase = blockIdx.x * 64 + rg * 4;
#pragma unroll
    for (int r = 0; r < 4; ++r) {
        int v = vbase + r;
        if (v < n) {
            float s = scale[v];
            __hip_bfloat16 b0 = __float2bfloat16(s * acc[r].x);
            __hip_bfloat16 b1 = __float2bfloat16(s * acc[r].y);
            __hip_bfloat16 b2 = __float2bfloat16(s * acc[r].z);
            __hip_bfloat16 b3 = __float2bfloat16(s * acc[r].w);
            ushort4 u;
            u.x = *reinterpret_cast<unsigned short*>(&b0);
            u.y = *reinterpret_cast<unsigned short*>(&b1);
            u.z = *reinterpret_cast<unsigned short*>(&b2);
            u.w = *reinterpret_cast<unsigned short*>(&b3);
            *reinterpret_cast<ushort4*>(C + (long)v * NDIM + cg * 4) = u;   // 8 B store
        }
    }
}

// ---- aggregation: out[v,:] = relu( dinv[v]*(sum_e xws[src_e,:] + xws[v,:]) + b ) ----
// xws is bf16 -> 128 B per row gather. One wave per node, lane = dim, x4 unroll.
__global__ void agg_k(const __hip_bfloat16* __restrict__ xws, const float* __restrict__ dinv,
                      const int* __restrict__ start, const int* __restrict__ csr,
                      const float* __restrict__ bias, float* __restrict__ out, int n) {
    int t = threadIdx.x;
    int lane = t & 63;
    int v = blockIdx.x * 4 + (t >> 6);
    if (v >= n) return;
    int s0 = start[v];
    int d0 = start[v + 1] - s0;
    float a0 = 0.f, a1 = 0.f, a2 = 0.f, a3 = 0.f;
    int i = 0;
    for (; i + 4 <= d0; i += 4) {
        int j0 = csr[s0 + i + 0];
        int j1 = csr[s0 + i + 1];
        int j2 = csr[s0 + i + 2];
        int j3 = csr[s0 + i + 3];
        float x0 = __bfloat162float(xws[(long)j0 * NDIM + lane]);
        float x1 = __bfloat162float(xws[(long)j1 * NDIM + lane]);
        float x2 = __bfloat162float(xws[(long)j2 * NDIM + lane]);
        float x3 = __bfloat162float(xws[(long)j3 * NDIM + lane]);
        a0 += x0; a1 += x1; a2 += x2; a3 += x3;
    }
    for (; i < d0; ++i) a0 += __bfloat162float(xws[(long)csr[s0 + i] * NDIM + lane]);
    float acc = (a0 + a1) + (a2 + a3);
    acc += __bfloat162float(xws[(long)v * NDIM + lane]);   // self loop
    acc = acc * dinv[v] + bias[lane];
    out[(long)v * NDIM + lane] = fmaxf(acc, 0.f);
}

// ---- mean-pool (batch sorted): register accumulate, flush on graph change ----
#define POOL_TILE 256
__global__ void pool_k(const float* __restrict__ h, const int* __restrict__ batch,
                       float* __restrict__ pooled, int n) {
    int t = threadIdx.x;
    int lane = t & 63;
    int sub = t >> 6;                 // 0..3
    int base = blockIdx.x * POOL_TILE;
    int gcur = -1;
    float acc = 0.f;
    for (int k = 0; k < POOL_TILE / 4; ++k) {
        int v = base + sub + 4 * k;   // monotone per thread -> few graph changes
        if (v < n) {
            int g = batch[v];
            if (g != gcur) {
                if (gcur >= 0) atomicAdd(&pooled[gcur * NDIM + lane], acc);
                gcur = g;
                acc = 0.f;
            }
            acc += h[(long)v * NDIM + lane];
        }
    }
    if (gcur >= 0) atomicAdd(&pooled[gcur * NDIM + lane], acc);
}

// ---- head: out[g,c] = (pooled[g,:]/max(cnt,1)) @ Wlin + blin ----
__global__ void final_k(const float* __restrict__ pooled, const int* __restrict__ gstart,
                        const int* __restrict__ gend,
                        const float* __restrict__ Wlin, const float* __restrict__ blin,
                        float* __restrict__ out, int nclass) {
    int t = blockIdx.x * blockDim.x + threadIdx.x;
    if (t >= NGRAPH * nclass) return;
    int g = t / nclass, c = t % nclass;
    float cnt = (float)(gend[g] - gstart[g]);
    float inv = 1.f / fmaxf(cnt, 1.f);
    float acc = 0.f;
    for (int j = 0; j < NDIM; ++j) acc += pooled[g * NDIM + j] * Wlin[j * nclass + c];
    out[t] = acc * inv + blin[c];
}

extern "C" void kernel_launch(void* const* d_in, const int* in_sizes, int n_in,
                              void* d_out, int out_size, void* d_ws, size_t ws_size,
                              hipStream_t stream) {
    const float* x     = (const float*)d_in[0];
    const int*   ei    = (const int*)d_in[1];
    const int*   batch = (const int*)d_in[2];
    const float* W1    = (const float*)d_in[3];
    const float* b1    = (const float*)d_in[4];
    const float* W2    = (const float*)d_in[5];
    const float* b2    = (const float*)d_in[6];
    const float* Wlin  = (const float*)d_in[7];
    const float* blin  = (const float*)d_in[8];
    float* out = (float*)d_out;

    const int N = in_sizes[0] / NDIM;        // 100000
    const int E = in_sizes[1] / 2;           // 1600000
    const int NCLASS = in_sizes[7] / NDIM;   // 10
    const int* src = ei;
    const int* dst = ei + E;
    const int NB   = (N + BNODES - 1) >> BSHIFT;        // 782 buckets (<=1024)
    const int NBLK = (E + ECHUNK - 1) / ECHUNK;         // 98 edge blocks (<=256)

    // ---- workspace carve-out (each 256B-aligned) ----
    size_t o = 0;
    char* wsp = (char*)d_ws;
    auto take = [&](size_t nbytes) -> void* {
        void* p = (void*)(wsp + o);
        o += (nbytes + 255) & ~(size_t)255;
        return p;
    };
    int*   gstart    = (int*)take(NGRAPH * 4);
    int*   gend      = (int*)take(NGRAPH * 4);
    float* pooled    = (float*)take(NGRAPH * NDIM * 4);
    size_t zero_bytes = o;                    // everything above must start at 0
    int*   cntmat   = (int*)take((size_t)NBLK * NB * 4);
    int*   basemat  = (int*)take((size_t)NBLK * NB * 4);
    int*   bucketTot   = (int*)take((size_t)NB * 4);
    int*   bucketStart = (int*)take((size_t)(NB + 1) * 4);
    float* dinv  = (float*)take((size_t)N * 4);
    int*   start = (int*)take((size_t)(N + 1) * 4);
    int*   csr   = (int*)take((size_t)E * 4);
    unsigned int* ebuf = (unsigned int*)take((size_t)E * 4);
    __hip_bfloat16* xws = (__hip_bfloat16*)take((size_t)N * NDIM * 2);
    float* h     = (float*)take((size_t)N * NDIM * 4);
    (void)ws_size;

    hipMemsetAsync(d_ws, 0, zero_bytes, stream);

    int rbl = (N + 3) / 4;                    // 4 nodes per block (agg)
    int gbl = (N + 63) / 64;                  // 64 rows per block (gemm)

    // CSR build (deterministic two-pass binning, zero global atomics)
    bincnt_k<<<NBLK, 256, (size_t)NB * 4, stream>>>(dst, cntmat, E, NB);
    colscan_k<<<NB, 256, 0, stream>>>(cntmat, basemat, bucketTot, NBLK, NB);
    bscan_k<<<1, 1024, 0, stream>>>(bucketTot, bucketStart, start, NB, N, E);
    bscatter_k<<<NBLK, 256, (size_t)NB * 4, stream>>>(src, dst, bucketStart, basemat, ebuf, E, NB);
    fill2_k<<<NB, 256, 0, stream>>>(ebuf, bucketStart, batch, dinv, start, csr, gstart, gend, N);

    // layer 1
    gemm_k<<<gbl, 256, 0, stream>>>(x, W1, dinv, xws, N);
    agg_k<<<rbl, 256, 0, stream>>>(xws, dinv, start, csr, b1, h, N);
    // layer 2
    gemm_k<<<gbl, 256, 0, stream>>>(h, W2, dinv, xws, N);
    agg_k<<<rbl, 256, 0, stream>>>(xws, dinv, start, csr, b2, h, N);

    // pooling + head
    pool_k<<<(N + POOL_TILE - 1) / POOL_TILE, 256, 0, stream>>>(h, batch, pooled, N);
    final_k<<<(NGRAPH * NCLASS + 255) / 256, 256, 0, stream>>>(pooled, gstart, gend, Wlin, blin, out, NCLASS);
}

// Round 8
// 1035.247 us; speedup vs baseline: 1.0833x; 1.0833x over previous
//
#include <hip/hip_runtime.h>
#include <hip/hip_bf16.h>

// GCN: h1 = relu(Â (x W1) + b1); h2 = relu(Â (h1 W2) + b2);
// out = mean_pool(h2, batch) @ Wlin + blin,  Â = D^-1/2 (A+I) D^-1/2
//
// R2: per-graph counts via sorted-batch boundaries.
// R3: norm folded into gemm epilogue (xws = dinv*xw); agg unrolled x4.
// R5/R6: bucketed CSR build, deterministic two-pass, zero global atomics.
// R7: xws bf16 (agg row gather 128 B) -- kept. gemm float4/bf16-struct
//     rewrite moved 1.28 GB HBM (26x logical; scratch-spill signature) -- reverted.
// R8: scalar-only gemm: 16 rows/block, 4 outputs/thread, named scalar
//     accumulators, bf16 via bit-ops on unsigned short (no addressable
//     aggregates anywhere). ECHUNK back to 8192 (196 blocks > 98).

#define NDIM 64
#define NGRAPH 64
#define BSHIFT 7                      // 128 nodes per bucket
#define BNODES 128
#define ECHUNK 8192                   // edges per block in bincnt/bscatter (32/thread)

__device__ __forceinline__ unsigned short f32_to_bf16(float f) {
    unsigned int u = __float_as_uint(f);
    unsigned int r = 0x7FFFu + ((u >> 16) & 1u);   // round-to-nearest-even
    return (unsigned short)((u + r) >> 16);
}
__device__ __forceinline__ float bf16_to_f32(unsigned short s) {
    return __uint_as_float((unsigned int)s << 16);
}

// ---- pass 1: per-(block,bucket) edge counts via LDS histogram ----
__global__ void bincnt_k(const int* __restrict__ dst, int* __restrict__ cntmat,
                         int e, int nb) {
    extern __shared__ int hist[];
    int t = threadIdx.x;
    for (int i = t; i < nb; i += 256) hist[i] = 0;
    __syncthreads();
    int base = blockIdx.x * ECHUNK + t;
#pragma unroll
    for (int k = 0; k < 32; ++k) {
        int i = base + k * 256;
        if (i < e) atomicAdd(&hist[dst[i] >> BSHIFT], 1);   // LDS atomic
    }
    __syncthreads();
    long row = (long)blockIdx.x * nb;
    for (int i = t; i < nb; i += 256) cntmat[row + i] = hist[i];
}

// ---- pass 2: per-bucket exclusive scan across blocks (one block per bucket) ----
// requires nblk <= 256
__global__ void colscan_k(const int* __restrict__ cntmat, int* __restrict__ basemat,
                          int* __restrict__ bucketTot, int nblk, int nb) {
    __shared__ int s[256];
    int b = blockIdx.x;
    int t = threadIdx.x;
    int v = (t < nblk) ? cntmat[(long)t * nb + b] : 0;
    s[t] = v;
    __syncthreads();
    for (int off = 1; off < 256; off <<= 1) {
        int tmp = (t >= off) ? s[t - off] : 0;
        __syncthreads();
        s[t] += tmp;
        __syncthreads();
    }
    if (t < nblk) basemat[(long)t * nb + b] = s[t] - v;   // exclusive within column
    if (t == 255) bucketTot[b] = s[255];
}

// ---- pass 3: exclusive scan of bucket totals (single block, nb<=1024) ----
__global__ void bscan_k(const int* __restrict__ bucketTot, int* __restrict__ bucketStart,
                        int* __restrict__ start, int nb, int n, int e) {
    __shared__ int s[1024];
    int t = threadIdx.x;
    int v = (t < nb) ? bucketTot[t] : 0;
    s[t] = v;
    __syncthreads();
    for (int off = 1; off < 1024; off <<= 1) {
        int tmp = (t >= off) ? s[t - off] : 0;
        __syncthreads();
        s[t] += tmp;
        __syncthreads();
    }
    if (t < nb) bucketStart[t + 1] = s[t];
    if (t == 0) { bucketStart[0] = 0; start[n] = e; }   // CSR sentinel
}

// ---- pass 4: scatter packed (dst_local<<25 | src) via block-private LDS cursors ----
// MUST use the same edge->block assignment as bincnt_k.
__global__ void bscatter_k(const int* __restrict__ src, const int* __restrict__ dst,
                           const int* __restrict__ bucketStart,
                           const int* __restrict__ basemat,
                           unsigned int* __restrict__ ebuf, int e, int nb) {
    extern __shared__ int cur[];
    int t = threadIdx.x;
    long row = (long)blockIdx.x * nb;
    for (int i = t; i < nb; i += 256) cur[i] = bucketStart[i] + basemat[row + i];
    __syncthreads();
    int base = blockIdx.x * ECHUNK + t;
#pragma unroll
    for (int k = 0; k < 32; ++k) {
        int i = base + k * 256;
        if (i < e) {
            int d = dst[i];
            int b = d >> BSHIFT;
            int pos = atomicAdd(&cur[b], 1);               // LDS atomic, block-private
            ebuf[pos] = ((unsigned)(d & (BNODES - 1)) << 25) | (unsigned)src[i];
        }
    }
}

// ---- pass 5: one block per bucket -> dst-ordered CSR slice, dinv, graph ranges ----
__global__ void fill2_k(const unsigned int* __restrict__ ebuf,
                        const int* __restrict__ bucketStart,
                        const int* __restrict__ batch, float* __restrict__ dinv,
                        int* __restrict__ start, int* __restrict__ csr,
                        int* __restrict__ gstart, int* __restrict__ gend, int n) {
    __shared__ int scnt[BNODES], sincl[BNODES], scur[BNODES];
    int t = threadIdx.x;
    int b = blockIdx.x;
    int node0 = b << BSHIFT;
    int nNodes = min(BNODES, n - node0);
    if (t < BNODES) scnt[t] = 0;
    int e0 = bucketStart[b], e1 = bucketStart[b + 1];
    __syncthreads();
    for (int i = e0 + t; i < e1; i += 256)
        atomicAdd(&scnt[ebuf[i] >> 25], 1);
    __syncthreads();
    int val = (t < BNODES) ? scnt[t] : 0;
    if (t < BNODES) sincl[t] = val;
    __syncthreads();
    for (int off = 1; off < BNODES; off <<= 1) {
        int tmp = (t >= off && t < BNODES) ? sincl[t - off] : 0;
        __syncthreads();
        if (t < BNODES) sincl[t] += tmp;
        __syncthreads();
    }
    if (t < nNodes) {
        int v = node0 + t;
        int st = e0 + sincl[t] - val;     // exclusive within bucket
        start[v] = st;
        scur[t] = st;
        dinv[v] = rsqrtf((float)(val + 1));
        int g = batch[v];                 // sorted-batch boundary detection
        if (v == 0 || batch[v - 1] != g) gstart[g] = v;
        if (v == n - 1 || batch[v + 1] != g) gend[g] = v + 1;
    }
    __syncthreads();
    for (int i = e0 + t; i < e1; i += 256) {
        unsigned rec = ebuf[i];
        int pos = atomicAdd(&scur[rec >> 25], 1);
        csr[pos] = (int)(rec & 0x1FFFFFFu);   // scatter within L2-local 8 KB slice
    }
}

// ---- dense GEMM  C[n,64](bf16 bits) = scale[row] * (A[n,64] @ W[64,64]) ----
// 16 rows per block; thread (w=t>>6, col=t&63) computes rows w,w+4,w+8,w+12
// at column col. Scalar-only: named float accumulators, no addressable locals.
__global__ void gemm_k(const float* __restrict__ A, const float* __restrict__ W,
                       const float* __restrict__ scale, unsigned short* __restrict__ C,
                       int n) {
    __shared__ float Wl[64 * 64];     // 16 KB
    __shared__ float Xl[16 * 64];     //  4 KB
    int t = threadIdx.x;
#pragma unroll
    for (int i = 0; i < 16; ++i) Wl[t + 256 * i] = W[t + 256 * i];
    long base = (long)blockIdx.x * (16 * 64);
    long lim  = (long)n * 64;
#pragma unroll
    for (int i = 0; i < 4; ++i) {
        long idx = base + t + 256 * i;
        Xl[t + 256 * i] = (idx < lim) ? A[idx] : 0.f;
    }
    __syncthreads();
    int w   = t >> 6;     // 0..3 (wave id)
    int col = t & 63;
    float a0 = 0.f, a1 = 0.f, a2 = 0.f, a3 = 0.f;
#pragma unroll
    for (int k = 0; k < 64; ++k) {
        float wv = Wl[k * 64 + col];          // stride-1 across wave (2-way, free)
        a0 += Xl[(w +  0) * 64 + k] * wv;     // wave-uniform broadcasts
        a1 += Xl[(w +  4) * 64 + k] * wv;
        a2 += Xl[(w +  8) * 64 + k] * wv;
        a3 += Xl[(w + 12) * 64 + k] * wv;
    }
    int v0 = blockIdx.x * 16;
    int v;
    v = v0 + w;      if (v < n) C[(long)v * NDIM + col] = f32_to_bf16(scale[v] * a0);
    v = v0 + w + 4;  if (v < n) C[(long)v * NDIM + col] = f32_to_bf16(scale[v] * a1);
    v = v0 + w + 8;  if (v < n) C[(long)v * NDIM + col] = f32_to_bf16(scale[v] * a2);
    v = v0 + w + 12; if (v < n) C[(long)v * NDIM + col] = f32_to_bf16(scale[v] * a3);
}

// ---- aggregation: out[v,:] = relu( dinv[v]*(sum_e xws[src_e,:] + xws[v,:]) + b ) ----
// xws is bf16 bits -> 128 B per row gather. One wave per node, lane = dim, x4 unroll.
__global__ void agg_k(const unsigned short* __restrict__ xws, const float* __restrict__ dinv,
                      const int* __restrict__ start, const int* __restrict__ csr,
                      const float* __restrict__ bias, float* __restrict__ out, int n) {
    int t = threadIdx.x;
    int lane = t & 63;
    int v = blockIdx.x * 4 + (t >> 6);
    if (v >= n) return;
    int s0 = start[v];
    int d0 = start[v + 1] - s0;
    float a0 = 0.f, a1 = 0.f, a2 = 0.f, a3 = 0.f;
    int i = 0;
    for (; i + 4 <= d0; i += 4) {
        int j0 = csr[s0 + i + 0];
        int j1 = csr[s0 + i + 1];
        int j2 = csr[s0 + i + 2];
        int j3 = csr[s0 + i + 3];
        float x0 = bf16_to_f32(xws[(long)j0 * NDIM + lane]);
        float x1 = bf16_to_f32(xws[(long)j1 * NDIM + lane]);
        float x2 = bf16_to_f32(xws[(long)j2 * NDIM + lane]);
        float x3 = bf16_to_f32(xws[(long)j3 * NDIM + lane]);
        a0 += x0; a1 += x1; a2 += x2; a3 += x3;
    }
    for (; i < d0; ++i) a0 += bf16_to_f32(xws[(long)csr[s0 + i] * NDIM + lane]);
    float acc = (a0 + a1) + (a2 + a3);
    acc += bf16_to_f32(xws[(long)v * NDIM + lane]);   // self loop
    acc = acc * dinv[v] + bias[lane];
    out[(long)v * NDIM + lane] = fmaxf(acc, 0.f);
}

// ---- mean-pool (batch sorted): register accumulate, flush on graph change ----
#define POOL_TILE 256
__global__ void pool_k(const float* __restrict__ h, const int* __restrict__ batch,
                       float* __restrict__ pooled, int n) {
    int t = threadIdx.x;
    int lane = t & 63;
    int sub = t >> 6;                 // 0..3
    int base = blockIdx.x * POOL_TILE;
    int gcur = -1;
    float acc = 0.f;
    for (int k = 0; k < POOL_TILE / 4; ++k) {
        int v = base + sub + 4 * k;   // monotone per thread -> few graph changes
        if (v < n) {
            int g = batch[v];
            if (g != gcur) {
                if (gcur >= 0) atomicAdd(&pooled[gcur * NDIM + lane], acc);
                gcur = g;
                acc = 0.f;
            }
            acc += h[(long)v * NDIM + lane];
        }
    }
    if (gcur >= 0) atomicAdd(&pooled[gcur * NDIM + lane], acc);
}

// ---- head: out[g,c] = (pooled[g,:]/max(cnt,1)) @ Wlin + blin ----
__global__ void final_k(const float* __restrict__ pooled, const int* __restrict__ gstart,
                        const int* __restrict__ gend,
                        const float* __restrict__ Wlin, const float* __restrict__ blin,
                        float* __restrict__ out, int nclass) {
    int t = blockIdx.x * blockDim.x + threadIdx.x;
    if (t >= NGRAPH * nclass) return;
    int g = t / nclass, c = t % nclass;
    float cnt = (float)(gend[g] - gstart[g]);
    float inv = 1.f / fmaxf(cnt, 1.f);
    float acc = 0.f;
    for (int j = 0; j < NDIM; ++j) acc += pooled[g * NDIM + j] * Wlin[j * nclass + c];
    out[t] = acc * inv + blin[c];
}

extern "C" void kernel_launch(void* const* d_in, const int* in_sizes, int n_in,
                              void* d_out, int out_size, void* d_ws, size_t ws_size,
                              hipStream_t stream) {
    const float* x     = (const float*)d_in[0];
    const int*   ei    = (const int*)d_in[1];
    const int*   batch = (const int*)d_in[2];
    const float* W1    = (const float*)d_in[3];
    const float* b1    = (const float*)d_in[4];
    const float* W2    = (const float*)d_in[5];
    const float* b2    = (const float*)d_in[6];
    const float* Wlin  = (const float*)d_in[7];
    const float* blin  = (const float*)d_in[8];
    float* out = (float*)d_out;

    const int N = in_sizes[0] / NDIM;        // 100000
    const int E = in_sizes[1] / 2;           // 1600000
    const int NCLASS = in_sizes[7] / NDIM;   // 10
    const int* src = ei;
    const int* dst = ei + E;
    const int NB   = (N + BNODES - 1) >> BSHIFT;        // 782 buckets (<=1024)
    const int NBLK = (E + ECHUNK - 1) / ECHUNK;         // 196 edge blocks (<=256)

    // ---- workspace carve-out (each 256B-aligned) ----
    size_t o = 0;
    char* wsp = (char*)d_ws;
    auto take = [&](size_t nbytes) -> void* {
        void* p = (void*)(wsp + o);
        o += (nbytes + 255) & ~(size_t)255;
        return p;
    };
    int*   gstart    = (int*)take(NGRAPH * 4);
    int*   gend      = (int*)take(NGRAPH * 4);
    float* pooled    = (float*)take(NGRAPH * NDIM * 4);
    size_t zero_bytes = o;                    // everything above must start at 0
    int*   cntmat   = (int*)take((size_t)NBLK * NB * 4);
    int*   basemat  = (int*)take((size_t)NBLK * NB * 4);
    int*   bucketTot   = (int*)take((size_t)NB * 4);
    int*   bucketStart = (int*)take((size_t)(NB + 1) * 4);
    float* dinv  = (float*)take((size_t)N * 4);
    int*   start = (int*)take((size_t)(N + 1) * 4);
    int*   csr   = (int*)take((size_t)E * 4);
    unsigned int* ebuf = (unsigned int*)take((size_t)E * 4);
    unsigned short* xws = (unsigned short*)take((size_t)N * NDIM * 2);
    float* h     = (float*)take((size_t)N * NDIM * 4);
    (void)ws_size;

    hipMemsetAsync(d_ws, 0, zero_bytes, stream);

    int rbl = (N + 3) / 4;                    // 4 nodes per block (agg)
    int gbl = (N + 15) / 16;                  // 16 rows per block (gemm)

    // CSR build (deterministic two-pass binning, zero global atomics)
    bincnt_k<<<NBLK, 256, (size_t)NB * 4, stream>>>(dst, cntmat, E, NB);
    colscan_k<<<NB, 256, 0, stream>>>(cntmat, basemat, bucketTot, NBLK, NB);
    bscan_k<<<1, 1024, 0, stream>>>(bucketTot, bucketStart, start, NB, N, E);
    bscatter_k<<<NBLK, 256, (size_t)NB * 4, stream>>>(src, dst, bucketStart, basemat, ebuf, E, NB);
    fill2_k<<<NB, 256, 0, stream>>>(ebuf, bucketStart, batch, dinv, start, csr, gstart, gend, N);

    // layer 1
    gemm_k<<<gbl, 256, 0, stream>>>(x, W1, dinv, xws, N);
    agg_k<<<rbl, 256, 0, stream>>>(xws, dinv, start, csr, b1, h, N);
    // layer 2
    gemm_k<<<gbl, 256, 0, stream>>>(h, W2, dinv, xws, N);
    agg_k<<<rbl, 256, 0, stream>>>(xws, dinv, start, csr, b2, h, N);

    // pooling + head
    pool_k<<<(N + POOL_TILE - 1) / POOL_TILE, 256, 0, stream>>>(h, batch, pooled, N);
    final_k<<<(NGRAPH * NCLASS + 255) / 256, 256, 0, stream>>>(pooled, gstart, gend, Wlin, blin, out, NCLASS);
}

// Round 9
// 391.071 us; speedup vs baseline: 2.8676x; 2.6472x over previous
//
#include <hip/hip_runtime.h>
#include <hip/hip_bf16.h>

// GCN: h1 = relu(Â (x W1) + b1); h2 = relu(Â (h1 W2) + b2);
// out = mean_pool(h2, batch) @ Wlin + blin,  Â = D^-1/2 (A+I) D^-1/2
//
// R2: per-graph counts via sorted-batch boundaries.
// R3: norm folded into gemm epilogue (xws = dinv*xw); agg unrolled x4.
// R5/R6: bucketed CSR build, deterministic two-pass, zero global atomics.
// R7: xws bf16 -> agg row gather 128 B (kept).
// R7/R8 LESSON: bf16 stores below dword width (2 B scalar or punned short4)
//     blew gemm up to 1.0-1.5 GB of HBM traffic (WRITE 987 MB vs 12.8 MB
//     logical) -- L2 write-merge fails for sub-dword lane stores.
// R9: gemm reverted to the R6-proven 64x64-LDS/4-row structure; epilogue
//     packs 2 bf16 across lane pairs (shfl_xor) and even lanes store ONE
//     dword -> 128 B/wave contiguous dword stores.

#define NDIM 64
#define NGRAPH 64
#define BSHIFT 7                      // 128 nodes per bucket
#define BNODES 128
#define ECHUNK 8192                   // edges per block in bincnt/bscatter (32/thread)

__device__ __forceinline__ unsigned short f32_to_bf16(float f) {
    unsigned int u = __float_as_uint(f);
    unsigned int r = 0x7FFFu + ((u >> 16) & 1u);   // round-to-nearest-even
    return (unsigned short)((u + r) >> 16);
}
__device__ __forceinline__ float bf16_to_f32(unsigned short s) {
    return __uint_as_float((unsigned int)s << 16);
}

// ---- pass 1: per-(block,bucket) edge counts via LDS histogram ----
__global__ void bincnt_k(const int* __restrict__ dst, int* __restrict__ cntmat,
                         int e, int nb) {
    extern __shared__ int hist[];
    int t = threadIdx.x;
    for (int i = t; i < nb; i += 256) hist[i] = 0;
    __syncthreads();
    int base = blockIdx.x * ECHUNK + t;
#pragma unroll
    for (int k = 0; k < 32; ++k) {
        int i = base + k * 256;
        if (i < e) atomicAdd(&hist[dst[i] >> BSHIFT], 1);   // LDS atomic
    }
    __syncthreads();
    long row = (long)blockIdx.x * nb;
    for (int i = t; i < nb; i += 256) cntmat[row + i] = hist[i];
}

// ---- pass 2: per-bucket exclusive scan across blocks (one block per bucket) ----
// requires nblk <= 256
__global__ void colscan_k(const int* __restrict__ cntmat, int* __restrict__ basemat,
                          int* __restrict__ bucketTot, int nblk, int nb) {
    __shared__ int s[256];
    int b = blockIdx.x;
    int t = threadIdx.x;
    int v = (t < nblk) ? cntmat[(long)t * nb + b] : 0;
    s[t] = v;
    __syncthreads();
    for (int off = 1; off < 256; off <<= 1) {
        int tmp = (t >= off) ? s[t - off] : 0;
        __syncthreads();
        s[t] += tmp;
        __syncthreads();
    }
    if (t < nblk) basemat[(long)t * nb + b] = s[t] - v;   // exclusive within column
    if (t == 255) bucketTot[b] = s[255];
}

// ---- pass 3: exclusive scan of bucket totals (single block, nb<=1024) ----
__global__ void bscan_k(const int* __restrict__ bucketTot, int* __restrict__ bucketStart,
                        int* __restrict__ start, int nb, int n, int e) {
    __shared__ int s[1024];
    int t = threadIdx.x;
    int v = (t < nb) ? bucketTot[t] : 0;
    s[t] = v;
    __syncthreads();
    for (int off = 1; off < 1024; off <<= 1) {
        int tmp = (t >= off) ? s[t - off] : 0;
        __syncthreads();
        s[t] += tmp;
        __syncthreads();
    }
    if (t < nb) bucketStart[t + 1] = s[t];
    if (t == 0) { bucketStart[0] = 0; start[n] = e; }   // CSR sentinel
}

// ---- pass 4: scatter packed (dst_local<<25 | src) via block-private LDS cursors ----
// MUST use the same edge->block assignment as bincnt_k.
__global__ void bscatter_k(const int* __restrict__ src, const int* __restrict__ dst,
                           const int* __restrict__ bucketStart,
                           const int* __restrict__ basemat,
                           unsigned int* __restrict__ ebuf, int e, int nb) {
    extern __shared__ int cur[];
    int t = threadIdx.x;
    long row = (long)blockIdx.x * nb;
    for (int i = t; i < nb; i += 256) cur[i] = bucketStart[i] + basemat[row + i];
    __syncthreads();
    int base = blockIdx.x * ECHUNK + t;
#pragma unroll
    for (int k = 0; k < 32; ++k) {
        int i = base + k * 256;
        if (i < e) {
            int d = dst[i];
            int b = d >> BSHIFT;
            int pos = atomicAdd(&cur[b], 1);               // LDS atomic, block-private
            ebuf[pos] = ((unsigned)(d & (BNODES - 1)) << 25) | (unsigned)src[i];
        }
    }
}

// ---- pass 5: one block per bucket -> dst-ordered CSR slice, dinv, graph ranges ----
__global__ void fill2_k(const unsigned int* __restrict__ ebuf,
                        const int* __restrict__ bucketStart,
                        const int* __restrict__ batch, float* __restrict__ dinv,
                        int* __restrict__ start, int* __restrict__ csr,
                        int* __restrict__ gstart, int* __restrict__ gend, int n) {
    __shared__ int scnt[BNODES], sincl[BNODES], scur[BNODES];
    int t = threadIdx.x;
    int b = blockIdx.x;
    int node0 = b << BSHIFT;
    int nNodes = min(BNODES, n - node0);
    if (t < BNODES) scnt[t] = 0;
    int e0 = bucketStart[b], e1 = bucketStart[b + 1];
    __syncthreads();
    for (int i = e0 + t; i < e1; i += 256)
        atomicAdd(&scnt[ebuf[i] >> 25], 1);
    __syncthreads();
    int val = (t < BNODES) ? scnt[t] : 0;
    if (t < BNODES) sincl[t] = val;
    __syncthreads();
    for (int off = 1; off < BNODES; off <<= 1) {
        int tmp = (t >= off && t < BNODES) ? sincl[t - off] : 0;
        __syncthreads();
        if (t < BNODES) sincl[t] += tmp;
        __syncthreads();
    }
    if (t < nNodes) {
        int v = node0 + t;
        int st = e0 + sincl[t] - val;     // exclusive within bucket
        start[v] = st;
        scur[t] = st;
        dinv[v] = rsqrtf((float)(val + 1));
        int g = batch[v];                 // sorted-batch boundary detection
        if (v == 0 || batch[v - 1] != g) gstart[g] = v;
        if (v == n - 1 || batch[v + 1] != g) gend[g] = v + 1;
    }
    __syncthreads();
    for (int i = e0 + t; i < e1; i += 256) {
        unsigned rec = ebuf[i];
        int pos = atomicAdd(&scur[rec >> 25], 1);
        csr[pos] = (int)(rec & 0x1FFFFFFu);   // scatter within L2-local 8 KB slice
    }
}

// ---- dense GEMM  C[n,64](bf16 bits) = scale[row] * (A[n,64] @ W[64,64]) ----
// R6-proven structure: 4 rows/block, W 64x64 in LDS, float4 LDS reads.
// Epilogue: pack bf16 pair across lane pairs; even lanes store ONE dword
// (128 B/wave contiguous dword stores -- never sub-dword).
__global__ void gemm_k(const float* __restrict__ A, const float* __restrict__ W,
                       const float* __restrict__ scale, unsigned int* __restrict__ C,
                       int n) {
    __shared__ float Wl[64 * 64];
    __shared__ float Xl[256];
    int t = threadIdx.x;
#pragma unroll
    for (int i = 0; i < 16; ++i) Wl[t + 256 * i] = W[t + 256 * i];
    long base = (long)blockIdx.x * 256;
    Xl[t] = (base + t < (long)n * NDIM) ? A[base + t] : 0.f;
    __syncthreads();
    int row = t >> 6, col = t & 63;
    float acc = 0.f;
    const float4* Xv = (const float4*)&Xl[row * 64];
#pragma unroll
    for (int k4 = 0; k4 < 16; ++k4) {
        float4 xv = Xv[k4];
        acc += xv.x * Wl[(4 * k4 + 0) * 64 + col];
        acc += xv.y * Wl[(4 * k4 + 1) * 64 + col];
        acc += xv.z * Wl[(4 * k4 + 2) * 64 + col];
        acc += xv.w * Wl[(4 * k4 + 3) * 64 + col];
    }
    int v = blockIdx.x * 4 + row;
    float mine = (v < n) ? scale[v] * acc : 0.f;
    float other = __shfl_xor(mine, 1);       // partner col's value
    // even lane: mine = col (even), other = col+1
    unsigned int u = ((unsigned int)f32_to_bf16(other) << 16) | (unsigned int)f32_to_bf16(mine);
    if ((col & 1) == 0 && v < n)
        C[(long)v * (NDIM / 2) + (col >> 1)] = u;   // dword store, 128 B/wave
}

// ---- aggregation: out[v,:] = relu( dinv[v]*(sum_e xws[src_e,:] + xws[v,:]) + b ) ----
// xws is bf16 bits -> 128 B per row gather. One wave per node, lane = dim, x4 unroll.
__global__ void agg_k(const unsigned short* __restrict__ xws, const float* __restrict__ dinv,
                      const int* __restrict__ start, const int* __restrict__ csr,
                      const float* __restrict__ bias, float* __restrict__ out, int n) {
    int t = threadIdx.x;
    int lane = t & 63;
    int v = blockIdx.x * 4 + (t >> 6);
    if (v >= n) return;
    int s0 = start[v];
    int d0 = start[v + 1] - s0;
    float a0 = 0.f, a1 = 0.f, a2 = 0.f, a3 = 0.f;
    int i = 0;
    for (; i + 4 <= d0; i += 4) {
        int j0 = csr[s0 + i + 0];
        int j1 = csr[s0 + i + 1];
        int j2 = csr[s0 + i + 2];
        int j3 = csr[s0 + i + 3];
        float x0 = bf16_to_f32(xws[(long)j0 * NDIM + lane]);
        float x1 = bf16_to_f32(xws[(long)j1 * NDIM + lane]);
        float x2 = bf16_to_f32(xws[(long)j2 * NDIM + lane]);
        float x3 = bf16_to_f32(xws[(long)j3 * NDIM + lane]);
        a0 += x0; a1 += x1; a2 += x2; a3 += x3;
    }
    for (; i < d0; ++i) a0 += bf16_to_f32(xws[(long)csr[s0 + i] * NDIM + lane]);
    float acc = (a0 + a1) + (a2 + a3);
    acc += bf16_to_f32(xws[(long)v * NDIM + lane]);   // self loop
    acc = acc * dinv[v] + bias[lane];
    out[(long)v * NDIM + lane] = fmaxf(acc, 0.f);
}

// ---- mean-pool (batch sorted): register accumulate, flush on graph change ----
#define POOL_TILE 256
__global__ void pool_k(const float* __restrict__ h, const int* __restrict__ batch,
                       float* __restrict__ pooled, int n) {
    int t = threadIdx.x;
    int lane = t & 63;
    int sub = t >> 6;                 // 0..3
    int base = blockIdx.x * POOL_TILE;
    int gcur = -1;
    float acc = 0.f;
    for (int k = 0; k < POOL_TILE / 4; ++k) {
        int v = base + sub + 4 * k;   // monotone per thread -> few graph changes
        if (v < n) {
            int g = batch[v];
            if (g != gcur) {
                if (gcur >= 0) atomicAdd(&pooled[gcur * NDIM + lane], acc);
                gcur = g;
                acc = 0.f;
            }
            acc += h[(long)v * NDIM + lane];
        }
    }
    if (gcur >= 0) atomicAdd(&pooled[gcur * NDIM + lane], acc);
}

// ---- head: out[g,c] = (pooled[g,:]/max(cnt,1)) @ Wlin + blin ----
__global__ void final_k(const float* __restrict__ pooled, const int* __restrict__ gstart,
                        const int* __restrict__ gend,
                        const float* __restrict__ Wlin, const float* __restrict__ blin,
                        float* __restrict__ out, int nclass) {
    int t = blockIdx.x * blockDim.x + threadIdx.x;
    if (t >= NGRAPH * nclass) return;
    int g = t / nclass, c = t % nclass;
    float cnt = (float)(gend[g] - gstart[g]);
    float inv = 1.f / fmaxf(cnt, 1.f);
    float acc = 0.f;
    for (int j = 0; j < NDIM; ++j) acc += pooled[g * NDIM + j] * Wlin[j * nclass + c];
    out[t] = acc * inv + blin[c];
}

extern "C" void kernel_launch(void* const* d_in, const int* in_sizes, int n_in,
                              void* d_out, int out_size, void* d_ws, size_t ws_size,
                              hipStream_t stream) {
    const float* x     = (const float*)d_in[0];
    const int*   ei    = (const int*)d_in[1];
    const int*   batch = (const int*)d_in[2];
    const float* W1    = (const float*)d_in[3];
    const float* b1    = (const float*)d_in[4];
    const float* W2    = (const float*)d_in[5];
    const float* b2    = (const float*)d_in[6];
    const float* Wlin  = (const float*)d_in[7];
    const float* blin  = (const float*)d_in[8];
    float* out = (float*)d_out;

    const int N = in_sizes[0] / NDIM;        // 100000
    const int E = in_sizes[1] / 2;           // 1600000
    const int NCLASS = in_sizes[7] / NDIM;   // 10
    const int* src = ei;
    const int* dst = ei + E;
    const int NB   = (N + BNODES - 1) >> BSHIFT;        // 782 buckets (<=1024)
    const int NBLK = (E + ECHUNK - 1) / ECHUNK;         // 196 edge blocks (<=256)

    // ---- workspace carve-out (each 256B-aligned) ----
    size_t o = 0;
    char* wsp = (char*)d_ws;
    auto take = [&](size_t nbytes) -> void* {
        void* p = (void*)(wsp + o);
        o += (nbytes + 255) & ~(size_t)255;
        return p;
    };
    int*   gstart    = (int*)take(NGRAPH * 4);
    int*   gend      = (int*)take(NGRAPH * 4);
    float* pooled    = (float*)take(NGRAPH * NDIM * 4);
    size_t zero_bytes = o;                    // everything above must start at 0
    int*   cntmat   = (int*)take((size_t)NBLK * NB * 4);
    int*   basemat  = (int*)take((size_t)NBLK * NB * 4);
    int*   bucketTot   = (int*)take((size_t)NB * 4);
    int*   bucketStart = (int*)take((size_t)(NB + 1) * 4);
    float* dinv  = (float*)take((size_t)N * 4);
    int*   start = (int*)take((size_t)(N + 1) * 4);
    int*   csr   = (int*)take((size_t)E * 4);
    unsigned int* ebuf = (unsigned int*)take((size_t)E * 4);
    unsigned short* xws = (unsigned short*)take((size_t)N * NDIM * 2);
    float* h     = (float*)take((size_t)N * NDIM * 4);
    (void)ws_size;

    hipMemsetAsync(d_ws, 0, zero_bytes, stream);

    int rbl = (N + 3) / 4;                    // 4 nodes/rows per block (gemm/agg)

    // CSR build (deterministic two-pass binning, zero global atomics)
    bincnt_k<<<NBLK, 256, (size_t)NB * 4, stream>>>(dst, cntmat, E, NB);
    colscan_k<<<NB, 256, 0, stream>>>(cntmat, basemat, bucketTot, NBLK, NB);
    bscan_k<<<1, 1024, 0, stream>>>(bucketTot, bucketStart, start, NB, N, E);
    bscatter_k<<<NBLK, 256, (size_t)NB * 4, stream>>>(src, dst, bucketStart, basemat, ebuf, E, NB);
    fill2_k<<<NB, 256, 0, stream>>>(ebuf, bucketStart, batch, dinv, start, csr, gstart, gend, N);

    // layer 1
    gemm_k<<<rbl, 256, 0, stream>>>(x, W1, dinv, (unsigned int*)xws, N);
    agg_k<<<rbl, 256, 0, stream>>>(xws, dinv, start, csr, b1, h, N);
    // layer 2
    gemm_k<<<rbl, 256, 0, stream>>>(h, W2, dinv, (unsigned int*)xws, N);
    agg_k<<<rbl, 256, 0, stream>>>(xws, dinv, start, csr, b2, h, N);

    // pooling + head
    pool_k<<<(N + POOL_TILE - 1) / POOL_TILE, 256, 0, stream>>>(h, batch, pooled, N);
    final_k<<<(NGRAPH * NCLASS + 255) / 256, 256, 0, stream>>>(pooled, gstart, gend, Wlin, blin, out, NCLASS);
}

// Round 10
// 324.069 us; speedup vs baseline: 3.4605x; 1.2068x over previous
//
#include <hip/hip_runtime.h>
#include <hip/hip_bf16.h>

// GCN: h1 = relu(Â (x W1) + b1); h2 = relu(Â (h1 W2) + b2);
// out = mean_pool(h2, batch) @ Wlin + blin,  Â = D^-1/2 (A+I) D^-1/2
//
// R2: per-graph counts via sorted-batch boundaries.
// R3: norm folded into gemm epilogue (xws = dinv*xw).
// R5/R6: bucketed CSR build, deterministic two-pass, zero global atomics.
// R7: xws bf16 -> agg row gather 128 B.
// R8/R9 LESSON: sub-dword per-lane global stores defeat L2 write-merge
//     (987 MB vs 12.8 MB logical). All stores >= dword/lane.
// R10: agg v2 -- two edges per gather instruction (half-wave per row,
//     dword = 2 bf16 per lane), unroll 8 -> 4 gathers/iter (R9 issued 8).
//     gemm v3 -- 16 rows/block (W L2 traffic /4), 4 cols/thread via
//     float4 W reads (named locals only; no addressable aggregates).

#define NDIM 64
#define NGRAPH 64
#define BSHIFT 7                      // 128 nodes per bucket
#define BNODES 128
#define ECHUNK 8192                   // edges per block in bincnt/bscatter (32/thread)

__device__ __forceinline__ unsigned short f32_to_bf16(float f) {
    unsigned int u = __float_as_uint(f);
    unsigned int r = 0x7FFFu + ((u >> 16) & 1u);   // round-to-nearest-even
    return (unsigned short)((u + r) >> 16);
}

// ---- pass 1: per-(block,bucket) edge counts via LDS histogram ----
__global__ void bincnt_k(const int* __restrict__ dst, int* __restrict__ cntmat,
                         int e, int nb) {
    extern __shared__ int hist[];
    int t = threadIdx.x;
    for (int i = t; i < nb; i += 256) hist[i] = 0;
    __syncthreads();
    int base = blockIdx.x * ECHUNK + t;
#pragma unroll
    for (int k = 0; k < 32; ++k) {
        int i = base + k * 256;
        if (i < e) atomicAdd(&hist[dst[i] >> BSHIFT], 1);   // LDS atomic
    }
    __syncthreads();
    long row = (long)blockIdx.x * nb;
    for (int i = t; i < nb; i += 256) cntmat[row + i] = hist[i];
}

// ---- pass 2: per-bucket exclusive scan across blocks (one block per bucket) ----
__global__ void colscan_k(const int* __restrict__ cntmat, int* __restrict__ basemat,
                          int* __restrict__ bucketTot, int nblk, int nb) {
    __shared__ int s[256];
    int b = blockIdx.x;
    int t = threadIdx.x;
    int v = (t < nblk) ? cntmat[(long)t * nb + b] : 0;
    s[t] = v;
    __syncthreads();
    for (int off = 1; off < 256; off <<= 1) {
        int tmp = (t >= off) ? s[t - off] : 0;
        __syncthreads();
        s[t] += tmp;
        __syncthreads();
    }
    if (t < nblk) basemat[(long)t * nb + b] = s[t] - v;   // exclusive within column
    if (t == 255) bucketTot[b] = s[255];
}

// ---- pass 3: exclusive scan of bucket totals (single block, nb<=1024) ----
__global__ void bscan_k(const int* __restrict__ bucketTot, int* __restrict__ bucketStart,
                        int* __restrict__ start, int nb, int n, int e) {
    __shared__ int s[1024];
    int t = threadIdx.x;
    int v = (t < nb) ? bucketTot[t] : 0;
    s[t] = v;
    __syncthreads();
    for (int off = 1; off < 1024; off <<= 1) {
        int tmp = (t >= off) ? s[t - off] : 0;
        __syncthreads();
        s[t] += tmp;
        __syncthreads();
    }
    if (t < nb) bucketStart[t + 1] = s[t];
    if (t == 0) { bucketStart[0] = 0; start[n] = e; }   // CSR sentinel
}

// ---- pass 4: scatter packed (dst_local<<25 | src) via block-private LDS cursors ----
__global__ void bscatter_k(const int* __restrict__ src, const int* __restrict__ dst,
                           const int* __restrict__ bucketStart,
                           const int* __restrict__ basemat,
                           unsigned int* __restrict__ ebuf, int e, int nb) {
    extern __shared__ int cur[];
    int t = threadIdx.x;
    long row = (long)blockIdx.x * nb;
    for (int i = t; i < nb; i += 256) cur[i] = bucketStart[i] + basemat[row + i];
    __syncthreads();
    int base = blockIdx.x * ECHUNK + t;
#pragma unroll
    for (int k = 0; k < 32; ++k) {
        int i = base + k * 256;
        if (i < e) {
            int d = dst[i];
            int b = d >> BSHIFT;
            int pos = atomicAdd(&cur[b], 1);               // LDS atomic, block-private
            ebuf[pos] = ((unsigned)(d & (BNODES - 1)) << 25) | (unsigned)src[i];
        }
    }
}

// ---- pass 5: one block per bucket -> dst-ordered CSR slice, dinv, graph ranges ----
__global__ void fill2_k(const unsigned int* __restrict__ ebuf,
                        const int* __restrict__ bucketStart,
                        const int* __restrict__ batch, float* __restrict__ dinv,
                        int* __restrict__ start, int* __restrict__ csr,
                        int* __restrict__ gstart, int* __restrict__ gend, int n) {
    __shared__ int scnt[BNODES], sincl[BNODES], scur[BNODES];
    int t = threadIdx.x;
    int b = blockIdx.x;
    int node0 = b << BSHIFT;
    int nNodes = min(BNODES, n - node0);
    if (t < BNODES) scnt[t] = 0;
    int e0 = bucketStart[b], e1 = bucketStart[b + 1];
    __syncthreads();
    for (int i = e0 + t; i < e1; i += 256)
        atomicAdd(&scnt[ebuf[i] >> 25], 1);
    __syncthreads();
    int val = (t < BNODES) ? scnt[t] : 0;
    if (t < BNODES) sincl[t] = val;
    __syncthreads();
    for (int off = 1; off < BNODES; off <<= 1) {
        int tmp = (t >= off && t < BNODES) ? sincl[t - off] : 0;
        __syncthreads();
        if (t < BNODES) sincl[t] += tmp;
        __syncthreads();
    }
    if (t < nNodes) {
        int v = node0 + t;
        int st = e0 + sincl[t] - val;     // exclusive within bucket
        start[v] = st;
        scur[t] = st;
        dinv[v] = rsqrtf((float)(val + 1));
        int g = batch[v];                 // sorted-batch boundary detection
        if (v == 0 || batch[v - 1] != g) gstart[g] = v;
        if (v == n - 1 || batch[v + 1] != g) gend[g] = v + 1;
    }
    __syncthreads();
    for (int i = e0 + t; i < e1; i += 256) {
        unsigned rec = ebuf[i];
        int pos = atomicAdd(&scur[rec >> 25], 1);
        csr[pos] = (int)(rec & 0x1FFFFFFu);   // scatter within L2-local 8 KB slice
    }
}

// ---- dense GEMM  C[n,64](bf16 bits) = scale[row] * (A[n,64] @ W[64,64]) ----
// 16 rows/block; thread (row=t>>4, cg=t&15) computes cols 4cg..4cg+3.
// float4 W reads (named locals), scalar X broadcast; dword stores only.
__global__ void gemm_k(const float* __restrict__ A, const float* __restrict__ W,
                       const float* __restrict__ scale, unsigned int* __restrict__ C,
                       int n) {
    __shared__ float4 Wl4[64 * 16];   // 16 KB: W[k][4c..4c+3]
    __shared__ float  Xl[16 * 64];    //  4 KB
    int t = threadIdx.x;
    const float4* W4 = (const float4*)W;
#pragma unroll
    for (int i = 0; i < 4; ++i) Wl4[t + 256 * i] = W4[t + 256 * i];
    long base = (long)blockIdx.x * 1024;
    long lim  = (long)n * 64;
#pragma unroll
    for (int i = 0; i < 4; ++i) {
        long idx = base + t + 256 * i;
        Xl[t + 256 * i] = (idx < lim) ? A[idx] : 0.f;
    }
    __syncthreads();
    int row = t >> 4, cg = t & 15;
    float ax = 0.f, ay = 0.f, az = 0.f, aw = 0.f;
#pragma unroll
    for (int k = 0; k < 64; ++k) {
        float4 wv = Wl4[k * 16 + cg];      // 16 distinct 16B addrs, 4-way broadcast
        float  xv = Xl[row * 64 + k];      // wave-uniform-ish broadcast
        ax += xv * wv.x;
        ay += xv * wv.y;
        az += xv * wv.z;
        aw += xv * wv.w;
    }
    int v = blockIdx.x * 16 + row;
    if (v < n) {
        float s = scale[v];
        unsigned int ulo = ((unsigned int)f32_to_bf16(s * ay) << 16) | (unsigned int)f32_to_bf16(s * ax);
        unsigned int uhi = ((unsigned int)f32_to_bf16(s * aw) << 16) | (unsigned int)f32_to_bf16(s * az);
        long dbase = (long)v * (NDIM / 2) + cg * 2;
        C[dbase]     = ulo;               // dims 4cg,4cg+1
        C[dbase + 1] = uhi;               // dims 4cg+2,4cg+3
    }
}

// ---- aggregation v2: out[v,:] = relu( dinv[v]*(sum_e xws[src_e,:] + xws[v,:]) + b )
// One wave per node. Half-wave h=lane>>5 handles edges i+h; lane covers dim
// pair p=lane&31 via one dword (2 bf16) -> 2 edges per gather instruction.
__global__ void agg_k(const unsigned int* __restrict__ xp, const float* __restrict__ dinv,
                      const int* __restrict__ start, const int* __restrict__ csr,
                      const float* __restrict__ bias, float* __restrict__ out, int n) {
    int t = threadIdx.x;
    int lane = t & 63;
    int h = lane >> 5;                // 0/1: which edge of the pair
    int p = lane & 31;                // dim pair index (dims 2p, 2p+1)
    int v = blockIdx.x * 4 + (t >> 6);
    if (v >= n) return;
    int s0 = start[v];
    int d0 = start[v + 1] - s0;
    float l0 = 0.f, l1 = 0.f, l2 = 0.f, l3 = 0.f;   // low-dim partials
    float h0 = 0.f, h1 = 0.f, h2 = 0.f, h3 = 0.f;   // high-dim partials
    int i = 0;
    for (; i + 8 <= d0; i += 8) {
        int j0 = csr[s0 + i + 0 + h];
        int j1 = csr[s0 + i + 2 + h];
        int j2 = csr[s0 + i + 4 + h];
        int j3 = csr[s0 + i + 6 + h];
        unsigned int u0 = xp[(long)j0 * 32 + p];
        unsigned int u1 = xp[(long)j1 * 32 + p];
        unsigned int u2 = xp[(long)j2 * 32 + p];
        unsigned int u3 = xp[(long)j3 * 32 + p];
        l0 += __uint_as_float(u0 << 16);  h0 += __uint_as_float(u0 & 0xFFFF0000u);
        l1 += __uint_as_float(u1 << 16);  h1 += __uint_as_float(u1 & 0xFFFF0000u);
        l2 += __uint_as_float(u2 << 16);  h2 += __uint_as_float(u2 & 0xFFFF0000u);
        l3 += __uint_as_float(u3 << 16);  h3 += __uint_as_float(u3 & 0xFFFF0000u);
    }
    for (; i + 2 <= d0; i += 2) {
        int j = csr[s0 + i + h];
        unsigned int u = xp[(long)j * 32 + p];
        l0 += __uint_as_float(u << 16);
        h0 += __uint_as_float(u & 0xFFFF0000u);
    }
    if (i < d0 && h == 0) {               // odd leftover edge: half-wave 0 only
        int j = csr[s0 + i];
        unsigned int u = xp[(long)j * 32 + p];
        l0 += __uint_as_float(u << 16);
        h0 += __uint_as_float(u & 0xFFFF0000u);
    }
    float al = (l0 + l1) + (l2 + l3);
    float ah = (h0 + h1) + (h2 + h3);
    al += __shfl_xor(al, 32);             // merge the two half-waves
    ah += __shfl_xor(ah, 32);
    unsigned int us = xp[(long)v * 32 + p];               // self loop
    al += __uint_as_float(us << 16);
    ah += __uint_as_float(us & 0xFFFF0000u);
    int d = 2 * p + h;                    // h=0 stores even dim, h=1 odd dim
    float val = h ? ah : al;
    val = val * dinv[v] + bias[d];
    out[(long)v * NDIM + d] = fmaxf(val, 0.f);
}

// ---- mean-pool (batch sorted): register accumulate, flush on graph change ----
#define POOL_TILE 256
__global__ void pool_k(const float* __restrict__ h, const int* __restrict__ batch,
                       float* __restrict__ pooled, int n) {
    int t = threadIdx.x;
    int lane = t & 63;
    int sub = t >> 6;                 // 0..3
    int base = blockIdx.x * POOL_TILE;
    int gcur = -1;
    float acc = 0.f;
    for (int k = 0; k < POOL_TILE / 4; ++k) {
        int v = base + sub + 4 * k;   // monotone per thread -> few graph changes
        if (v < n) {
            int g = batch[v];
            if (g != gcur) {
                if (gcur >= 0) atomicAdd(&pooled[gcur * NDIM + lane], acc);
                gcur = g;
                acc = 0.f;
            }
            acc += h[(long)v * NDIM + lane];
        }
    }
    if (gcur >= 0) atomicAdd(&pooled[gcur * NDIM + lane], acc);
}

// ---- head: out[g,c] = (pooled[g,:]/max(cnt,1)) @ Wlin + blin ----
__global__ void final_k(const float* __restrict__ pooled, const int* __restrict__ gstart,
                        const int* __restrict__ gend,
                        const float* __restrict__ Wlin, const float* __restrict__ blin,
                        float* __restrict__ out, int nclass) {
    int t = blockIdx.x * blockDim.x + threadIdx.x;
    if (t >= NGRAPH * nclass) return;
    int g = t / nclass, c = t % nclass;
    float cnt = (float)(gend[g] - gstart[g]);
    float inv = 1.f / fmaxf(cnt, 1.f);
    float acc = 0.f;
    for (int j = 0; j < NDIM; ++j) acc += pooled[g * NDIM + j] * Wlin[j * nclass + c];
    out[t] = acc * inv + blin[c];
}

extern "C" void kernel_launch(void* const* d_in, const int* in_sizes, int n_in,
                              void* d_out, int out_size, void* d_ws, size_t ws_size,
                              hipStream_t stream) {
    const float* x     = (const float*)d_in[0];
    const int*   ei    = (const int*)d_in[1];
    const int*   batch = (const int*)d_in[2];
    const float* W1    = (const float*)d_in[3];
    const float* b1    = (const float*)d_in[4];
    const float* W2    = (const float*)d_in[5];
    const float* b2    = (const float*)d_in[6];
    const float* Wlin  = (const float*)d_in[7];
    const float* blin  = (const float*)d_in[8];
    float* out = (float*)d_out;

    const int N = in_sizes[0] / NDIM;        // 100000
    const int E = in_sizes[1] / 2;           // 1600000
    const int NCLASS = in_sizes[7] / NDIM;   // 10
    const int* src = ei;
    const int* dst = ei + E;
    const int NB   = (N + BNODES - 1) >> BSHIFT;        // 782 buckets (<=1024)
    const int NBLK = (E + ECHUNK - 1) / ECHUNK;         // 196 edge blocks (<=256)

    // ---- workspace carve-out (each 256B-aligned) ----
    size_t o = 0;
    char* wsp = (char*)d_ws;
    auto take = [&](size_t nbytes) -> void* {
        void* p = (void*)(wsp + o);
        o += (nbytes + 255) & ~(size_t)255;
        return p;
    };
    int*   gstart    = (int*)take(NGRAPH * 4);
    int*   gend      = (int*)take(NGRAPH * 4);
    float* pooled    = (float*)take(NGRAPH * NDIM * 4);
    size_t zero_bytes = o;                    // everything above must start at 0
    int*   cntmat   = (int*)take((size_t)NBLK * NB * 4);
    int*   basemat  = (int*)take((size_t)NBLK * NB * 4);
    int*   bucketTot   = (int*)take((size_t)NB * 4);
    int*   bucketStart = (int*)take((size_t)(NB + 1) * 4);
    float* dinv  = (float*)take((size_t)N * 4);
    int*   start = (int*)take((size_t)(N + 1) * 4);
    int*   csr   = (int*)take((size_t)E * 4);
    unsigned int* ebuf = (unsigned int*)take((size_t)E * 4);
    unsigned int* xws  = (unsigned int*)take((size_t)N * NDIM * 2);   // bf16 pairs
    float* h     = (float*)take((size_t)N * NDIM * 4);
    (void)ws_size;

    hipMemsetAsync(d_ws, 0, zero_bytes, stream);

    int rbl = (N + 3) / 4;                    // 4 nodes per block (agg)
    int gbl = (N + 15) / 16;                  // 16 rows per block (gemm)

    // CSR build (deterministic two-pass binning, zero global atomics)
    bincnt_k<<<NBLK, 256, (size_t)NB * 4, stream>>>(dst, cntmat, E, NB);
    colscan_k<<<NB, 256, 0, stream>>>(cntmat, basemat, bucketTot, NBLK, NB);
    bscan_k<<<1, 1024, 0, stream>>>(bucketTot, bucketStart, start, NB, N, E);
    bscatter_k<<<NBLK, 256, (size_t)NB * 4, stream>>>(src, dst, bucketStart, basemat, ebuf, E, NB);
    fill2_k<<<NB, 256, 0, stream>>>(ebuf, bucketStart, batch, dinv, start, csr, gstart, gend, N);

    // layer 1
    gemm_k<<<gbl, 256, 0, stream>>>(x, W1, dinv, xws, N);
    agg_k<<<rbl, 256, 0, stream>>>(xws, dinv, start, csr, b1, h, N);
    // layer 2
    gemm_k<<<gbl, 256, 0, stream>>>(h, W2, dinv, xws, N);
    agg_k<<<rbl, 256, 0, stream>>>(xws, dinv, start, csr, b2, h, N);

    // pooling + head
    pool_k<<<(N + POOL_TILE - 1) / POOL_TILE, 256, 0, stream>>>(h, batch, pooled, N);
    final_k<<<(NGRAPH * NCLASS + 255) / 256, 256, 0, stream>>>(pooled, gstart, gend, Wlin, blin, out, NCLASS);
}